// Round 4
// baseline (6704.917 us; speedup 1.0000x reference)
//
#include <hip/hip_runtime.h>
#include <hip/hip_cooperative_groups.h>
#include <math.h>

#define EE 1024
#define GG 2730
#define VV 16416
#define IMGT 256
#define NL 12
#define TENC 64
#define PROBS_N (8*VV)
#define SM_SZ 4608

namespace cg = cooperative_groups;
typedef long long i64;

// ---------------- reduction helpers ----------------
__device__ __forceinline__ float warpSum(float v) {
#pragma unroll
  for (int o = 32; o > 0; o >>= 1) v += __shfl_down(v, o, 64);
  return v;
}
__device__ __forceinline__ float warpMax(float v) {
#pragma unroll
  for (int o = 32; o > 0; o >>= 1) v = fmaxf(v, __shfl_down(v, o, 64));
  return v;
}
__device__ __forceinline__ int warpSumI(int v) {
#pragma unroll
  for (int o = 32; o > 0; o >>= 1) v += __shfl_down(v, o, 64);
  return v;
}
// 256-thread (4 wave) block reductions; sred = 4 floats of shared
__device__ __forceinline__ float bsum4(float v, float* sred) {
  int lane = threadIdx.x & 63, w = threadIdx.x >> 6;
  float r = warpSum(v);
  __syncthreads();
  if (lane == 0) sred[w] = r;
  __syncthreads();
  return sred[0] + sred[1] + sred[2] + sred[3];
}
__device__ __forceinline__ float bmax4(float v, float* sred) {
  int lane = threadIdx.x & 63, w = threadIdx.x >> 6;
  float r = warpMax(v);
  __syncthreads();
  if (lane == 0) sred[w] = r;
  __syncthreads();
  return fmaxf(fmaxf(sred[0], sred[1]), fmaxf(sred[2], sred[3]));
}
// 1024-thread (16 wave) block reductions (top-k kernel only)
__device__ __forceinline__ float bsum16(float v, float* sr) {
  int lane = threadIdx.x & 63, w = threadIdx.x >> 6;
  float r = warpSum(v);
  __syncthreads();
  if (lane == 0) sr[w] = r;
  __syncthreads();
  float s = 0.f;
#pragma unroll
  for (int i = 0; i < 16; ++i) s += sr[i];
  return s;
}
__device__ __forceinline__ float bmax16(float v, float* sr) {
  int lane = threadIdx.x & 63, w = threadIdx.x >> 6;
  float r = warpMax(v);
  __syncthreads();
  if (lane == 0) sr[w] = r;
  __syncthreads();
  float s = sr[0];
#pragma unroll
  for (int i = 1; i < 16; ++i) s = fmaxf(s, sr[i]);
  return s;
}
__device__ __forceinline__ int bsumI16(int v, int* sr) {
  int lane = threadIdx.x & 63, w = threadIdx.x >> 6;
  int r = warpSumI(v);
  __syncthreads();
  if (lane == 0) sr[w] = r;
  __syncthreads();
  int s = 0;
#pragma unroll
  for (int i = 0; i < 16; ++i) s += sr[i];
  return s;
}

// ---------------- params ----------------
struct Params {
  const float *enc, *ast_in;
  const int *prev, *tok;
  const float *embt, *embp, *lng, *lnb, *fing, *finb;
  const float *saq, *sak, *sav, *sao, *caq, *cak, *cav, *cao;
  const float *lnsg, *lnsb, *glug, *glub, *fc0, *fc1, *fc2w;
  float *ast_out;
  float *x, *h1, *oT, *h2p, *h3, *o2T, *h4p, *zT, *g0p, *g1p, *w2T, *fc2p, *xfT;
};

// ---------------- copy slice duty (blocks 16..255 during small stages) ---------
__device__ __forceinline__ void dev_copy(const Params& p, int sid, int bid, int t, int ti) {
  const long N4 = (long)NL * 32 * IMGT * (EE / 4);
  long cidx = (long)sid * 240 + (bid - 16);
  long start = cidx * 2098;
  long end = start + 2098; if (end > N4) end = N4;
  const float4* src = (const float4*)p.ast_in;
  float4* dst = (float4*)p.ast_out;
  for (long i = start + t; i < end; i += 256) {
    float4 v = src[i];
    int row = (int)((i >> 8) & 255);
    if (row != ti) dst[i] = v;   // row ti written by self-attn stages
  }
}

// ---------------- embed + LN (blocks 0..15) ----------------
__device__ __forceinline__ void dev_embed(const Params& p, int b, int t, float* sm) {
  float* sred = sm + 4544;
  int ti = p.tok[0];
  int id = p.prev[b & 7];
  float v[4]; float s = 0.f, s2 = 0.f;
#pragma unroll
  for (int j = 0; j < 4; ++j) {
    int i = t + j * 256;
    float val = p.embt[(i64)id * EE + i] + p.embp[(i64)ti * EE + i];
    v[j] = val; s += val; s2 += val * val;
  }
  s = bsum4(s, sred); s2 = bsum4(s2, sred);
  float m = s / EE, rs = rsqrtf(s2 / EE - m * m + 1e-5f);
#pragma unroll
  for (int j = 0; j < 4; ++j) {
    int i = t + j * 256;
    p.x[b * EE + i] = (v[j] - m) * rs * p.lng[i] + p.lnb[i];
  }
}

// ------- LN1: x += sum32(fc2p) (l>0) ; h1 = LN(x, g[0],b[0]) -------
__device__ __forceinline__ void dev_ln1(const Params& p, int l, int b, int t, float* sm) {
  float* sred = sm + 4544;
  const float* g0 = p.lnsg + (i64)l * 5 * EE;
  const float* b0 = p.lnsb + (i64)l * 5 * EE;
  float v[4];
#pragma unroll
  for (int j = 0; j < 4; ++j) v[j] = p.x[b * EE + t + j * 256];
  if (l > 0) {
#pragma unroll 4
    for (int n = 0; n < 32; ++n) {
      const float* pp = p.fc2p + ((i64)(n * 16 + b)) * EE + t;
#pragma unroll
      for (int j = 0; j < 4; ++j) v[j] += pp[j * 256];
    }
  }
  float s = 0.f, s2 = 0.f;
#pragma unroll
  for (int j = 0; j < 4; ++j) { s += v[j]; s2 += v[j] * v[j]; }
  s = bsum4(s, sred); s2 = bsum4(s2, sred);
  float m = s / EE, rs = rsqrtf(s2 / EE - m * m + 1e-5f);
#pragma unroll
  for (int j = 0; j < 4; ++j) {
    int i = t + j * 256;
    p.x[b * EE + i] = v[j];
    p.h1[b * EE + i] = (v[j] - m) * rs * g0[i] + b0[i];
  }
}

// ------- LN2: x += LN(sum16 h2p, g[1],b[1]) ; h3 = LN(x, g[2],b[2]) -------
__device__ __forceinline__ void dev_ln2(const Params& p, int l, int b, int t, float* sm) {
  float* sred = sm + 4544;
  const float* g1 = p.lnsg + (i64)l * 5 * EE + EE;
  const float* b1 = p.lnsb + (i64)l * 5 * EE + EE;
  const float* g2 = g1 + EE, *b2 = b1 + EE;
  float hv[4] = {0.f, 0.f, 0.f, 0.f};
#pragma unroll 4
  for (int n = 0; n < 16; ++n) {
    const float* pp = p.h2p + ((i64)(n * 16 + b)) * EE + t;
#pragma unroll
    for (int j = 0; j < 4; ++j) hv[j] += pp[j * 256];
  }
  float s = 0.f, s2 = 0.f;
#pragma unroll
  for (int j = 0; j < 4; ++j) { s += hv[j]; s2 += hv[j] * hv[j]; }
  s = bsum4(s, sred); s2 = bsum4(s2, sred);
  float m1 = s / EE, rs1 = rsqrtf(s2 / EE - m1 * m1 + 1e-5f);
  float xn[4]; float s3 = 0.f, s4 = 0.f;
#pragma unroll
  for (int j = 0; j < 4; ++j) {
    int i = t + j * 256;
    float val = p.x[b * EE + i] + (hv[j] - m1) * rs1 * g1[i] + b1[i];
    xn[j] = val; s3 += val; s4 += val * val;
  }
  s3 = bsum4(s3, sred); s4 = bsum4(s4, sred);
  float m2 = s3 / EE, rs2 = rsqrtf(s4 / EE - m2 * m2 + 1e-5f);
#pragma unroll
  for (int j = 0; j < 4; ++j) {
    int i = t + j * 256;
    p.x[b * EE + i] = xn[j];
    p.h3[b * EE + i] = (xn[j] - m2) * rs2 * g2[i] + b2[i];
  }
}

// ------- LN3: x += LN(sum16 h4p, g[3],b[3]) ; zT = LN(x, g[4],b[4]) transposed ----
__device__ __forceinline__ void dev_ln3(const Params& p, int l, int b, int t, float* sm) {
  float* sred = sm + 4544;
  const float* g1 = p.lnsg + (i64)l * 5 * EE + 3 * EE;
  const float* b1 = p.lnsb + (i64)l * 5 * EE + 3 * EE;
  const float* g2 = g1 + EE, *b2 = b1 + EE;
  float hv[4] = {0.f, 0.f, 0.f, 0.f};
#pragma unroll 4
  for (int n = 0; n < 16; ++n) {
    const float* pp = p.h4p + ((i64)(n * 16 + b)) * EE + t;
#pragma unroll
    for (int j = 0; j < 4; ++j) hv[j] += pp[j * 256];
  }
  float s = 0.f, s2 = 0.f;
#pragma unroll
  for (int j = 0; j < 4; ++j) { s += hv[j]; s2 += hv[j] * hv[j]; }
  s = bsum4(s, sred); s2 = bsum4(s2, sred);
  float m1 = s / EE, rs1 = rsqrtf(s2 / EE - m1 * m1 + 1e-5f);
  float xn[4]; float s3 = 0.f, s4 = 0.f;
#pragma unroll
  for (int j = 0; j < 4; ++j) {
    int i = t + j * 256;
    float val = p.x[b * EE + i] + (hv[j] - m1) * rs1 * g1[i] + b1[i];
    xn[j] = val; s3 += val; s4 += val * val;
  }
  s3 = bsum4(s3, sred); s4 = bsum4(s4, sred);
  float m2 = s3 / EE, rs2 = rsqrtf(s4 / EE - m2 * m2 + 1e-5f);
#pragma unroll
  for (int j = 0; j < 4; ++j) {
    int i = t + j * 256;
    p.x[b * EE + i] = xn[j];
    p.zT[(i64)i * 16 + b] = (xn[j] - m2) * rs2 * g2[i] + b2[i];
  }
}

// ------- final LN: xfT = LN(x + sum32 fc2p) transposed -------
__device__ __forceinline__ void dev_finalln(const Params& p, int b, int t, float* sm) {
  float* sred = sm + 4544;
  float v[4];
#pragma unroll
  for (int j = 0; j < 4; ++j) v[j] = p.x[b * EE + t + j * 256];
#pragma unroll 4
  for (int n = 0; n < 32; ++n) {
    const float* pp = p.fc2p + ((i64)(n * 16 + b)) * EE + t;
#pragma unroll
    for (int j = 0; j < 4; ++j) v[j] += pp[j * 256];
  }
  float s = 0.f, s2 = 0.f;
#pragma unroll
  for (int j = 0; j < 4; ++j) { s += v[j]; s2 += v[j] * v[j]; }
  s = bsum4(s, sred); s2 = bsum4(s2, sred);
  float m = s / EE, rs = rsqrtf(s2 / EE - m * m + 1e-5f);
#pragma unroll
  for (int j = 0; j < 4; ++j) {
    int i = t + j * 256;
    p.xfT[(i64)i * 16 + b] = (v[j] - m) * rs * p.fing[i] + p.finb[i];
  }
}

// ------- GLU middle: u = gelu(sum g0p)*(sum g1p); w2T = LN_G(u) transposed -------
__device__ __forceinline__ void dev_glu(const Params& p, int l, int b, int t, float* sm) {
  float* u = sm;
  float* sred = sm + 4544;
  const float* g = p.glug + (i64)l * GG;
  const float* bb = p.glub + (i64)l * GG;
  float s = 0.f, s2 = 0.f;
  for (int i = t; i < GG; i += 256) {
    float a = 0.f, c = 0.f;
#pragma unroll 4
    for (int n = 0; n < 16; ++n) {
      a += p.g0p[((i64)(n * 16 + b)) * GG + i];
      c += p.g1p[((i64)(n * 16 + b)) * GG + i];
    }
    float gel = 0.5f * a * (1.0f + erff(a * 0.70710678118654752f));
    float val = gel * c;
    u[i] = val; s += val; s2 += val * val;
  }
  s = bsum4(s, sred); s2 = bsum4(s2, sred);
  float m = s / GG, rs = rsqrtf(s2 / GG - m * m + 1e-5f);
  for (int i = t; i < GG; i += 256) p.w2T[(i64)i * 16 + b] = (u[i] - m) * rs * g[i] + bb[i];
}

// ---------------- self-attention (per (b,h) block) ----------------
__device__ __forceinline__ void dev_sa(const Params& p, int l, int b, int h, int t,
                                       int ti, float* sm) {
  float* lx = sm;               // 1024
  float* redq = sm + 1024, *redk = sm + 2048, *redv = sm + 3072;
  float* qs = sm + 4096, *ks = sm + 4160, *vs = sm + 4224;
  float* sc = sm + 4288;        // 256
  float* sred = sm + 4544;
  const i64 mo = (i64)l * EE * EE;
  const float* wq = p.saq + mo;
  const float* wk = p.sak + mo;
  const float* wv = p.sav + mo;
#pragma unroll
  for (int j = 0; j < 4; ++j) lx[t + j * 256] = p.h1[b * EE + t + j * 256];
  __syncthreads();
  int cg4 = (t & 15) * 4, es = t >> 4;
  {
    float4 aq = {0, 0, 0, 0}, ak = {0, 0, 0, 0}, av = {0, 0, 0, 0};
    const float* pq = wq + (i64)(es * 64) * EE + h * 64 + cg4;
    const float* pk = wk + (i64)(es * 64) * EE + h * 64 + cg4;
    const float* pv = wv + (i64)(es * 64) * EE + h * 64 + cg4;
#pragma unroll 4
    for (int e = 0; e < 64; ++e) {
      float xe = lx[es * 64 + e];
      float4 q4 = *(const float4*)(pq + (i64)e * EE);
      float4 k4 = *(const float4*)(pk + (i64)e * EE);
      float4 v4 = *(const float4*)(pv + (i64)e * EE);
      aq.x = fmaf(xe, q4.x, aq.x); aq.y = fmaf(xe, q4.y, aq.y);
      aq.z = fmaf(xe, q4.z, aq.z); aq.w = fmaf(xe, q4.w, aq.w);
      ak.x = fmaf(xe, k4.x, ak.x); ak.y = fmaf(xe, k4.y, ak.y);
      ak.z = fmaf(xe, k4.z, ak.z); ak.w = fmaf(xe, k4.w, ak.w);
      av.x = fmaf(xe, v4.x, av.x); av.y = fmaf(xe, v4.y, av.y);
      av.z = fmaf(xe, v4.z, av.z); av.w = fmaf(xe, v4.w, av.w);
    }
    *(float4*)&redq[es * 64 + cg4] = aq;
    *(float4*)&redk[es * 64 + cg4] = ak;
    *(float4*)&redv[es * 64 + cg4] = av;
  }
  __syncthreads();
  if (t < 64) {
    float q = 0.f, k = 0.f, v = 0.f;
#pragma unroll
    for (int s = 0; s < 16; ++s) {
      q += redq[s * 64 + t]; k += redk[s * 64 + t]; v += redv[s * 64 + t];
    }
    qs[t] = q * 0.125f; ks[t] = k; vs[t] = v;
    i64 base = (((i64)l * 32 + b) * IMGT + ti) * EE + h * 64 + t;
    p.ast_out[base] = k;
    p.ast_out[base + (i64)16 * IMGT * EE] = v;
  }
  __syncthreads();
  int NT = ti + 1;
  if (t < NT) {
    float s = 0.f;
    if (t == ti) {
#pragma unroll
      for (int i = 0; i < 64; ++i) s += qs[i] * ks[i];
    } else {
      const float4* kr = (const float4*)(p.ast_in + (((i64)l * 32 + b) * IMGT + t) * EE + h * 64);
#pragma unroll
      for (int i = 0; i < 16; ++i) {
        float4 kv = kr[i];
        s += qs[4 * i] * kv.x + qs[4 * i + 1] * kv.y + qs[4 * i + 2] * kv.z + qs[4 * i + 3] * kv.w;
      }
    }
    sc[t] = s;
  }
  __syncthreads();
  float mx = -3e38f;
  for (int i = t; i < NT; i += 256) mx = fmaxf(mx, sc[i]);
  mx = bmax4(mx, sred);
  float smv = 0.f;
  for (int i = t; i < NT; i += 256) { float pr = __expf(sc[i] - mx); sc[i] = pr; smv += pr; }
  smv = bsum4(smv, sred);
  int c2 = t & 63, seg = t >> 6;
  float oa = 0.f;
  const float* vbase = p.ast_in + ((i64)l * 32 + 16 + b) * IMGT * EE + h * 64 + c2;
  for (int tt = seg; tt < NT; tt += 4) {
    float pr = sc[tt];
    float vv2 = (tt == ti) ? vs[c2] : vbase[(i64)tt * EE];
    oa = fmaf(pr, vv2, oa);
  }
  __syncthreads();
  redq[seg * 64 + c2] = oa;
  __syncthreads();
  if (t < 64) {
    float o = (redq[t] + redq[64 + t] + redq[128 + t] + redq[192 + t]) / smv;
    p.oT[(i64)(h * 64 + t) * 16 + b] = o;
  }
  __syncthreads();
}

// ---------------- cross-attention (per (b,h) block) ----------------
__device__ __forceinline__ void dev_ca(const Params& p, int l, int b, int h, int t, float* sm) {
  float* lx = sm;              // 1024
  float* redq = sm + 1024;     // 1024
  float* q2 = sm + 2048;       // 64
  float* qk = sm + 2112;       // 1024
  float* ctx = sm + 3136;      // 1024
  float* pp = sm + 4160;       // 64
  const i64 mo = (i64)l * EE * EE;
  const float* wq = p.caq + mo;
  const float* wk = p.cak + mo;
  const float* wv = p.cav + mo;
  int c = t & 63, seg = t >> 6;
  int cg4 = (t & 15) * 4, es = t >> 4;
#pragma unroll
  for (int j = 0; j < 4; ++j) lx[t + j * 256] = p.h3[b * EE + t + j * 256];
  __syncthreads();
  {
    float4 a = {0, 0, 0, 0};
    const float* pq = wq + (i64)(es * 64) * EE + h * 64 + cg4;
#pragma unroll 4
    for (int e = 0; e < 64; ++e) {
      float xe = lx[es * 64 + e];
      float4 w4 = *(const float4*)(pq + (i64)e * EE);
      a.x = fmaf(xe, w4.x, a.x); a.y = fmaf(xe, w4.y, a.y);
      a.z = fmaf(xe, w4.z, a.z); a.w = fmaf(xe, w4.w, a.w);
    }
    *(float4*)&redq[es * 64 + cg4] = a;
  }
  __syncthreads();
  if (t < 64) {
    float q = 0.f;
#pragma unroll
    for (int s = 0; s < 16; ++s) q += redq[s * 64 + t];
    q2[t] = q * 0.125f;
  }
  __syncthreads();
#pragma unroll
  for (int j = 0; j < 4; ++j) {
    int e = t + j * 256;
    const float4* wr = (const float4*)(wk + (i64)e * EE + h * 64);
    float s = 0.f;
#pragma unroll
    for (int i = 0; i < 16; ++i) {
      float4 w4 = wr[i];
      s += q2[4 * i] * w4.x + q2[4 * i + 1] * w4.y + q2[4 * i + 2] * w4.z + q2[4 * i + 3] * w4.w;
    }
    qk[e] = s;
  }
  __syncthreads();
  {
    const float4* er = (const float4*)(p.enc + ((i64)b * TENC + c) * EE + seg * 256);
    float s = 0.f;
#pragma unroll 8
    for (int i = 0; i < 64; ++i) {
      float4 ev = er[i];
      int e = seg * 256 + 4 * i;
      s += qk[e] * ev.x + qk[e + 1] * ev.y + qk[e + 2] * ev.z + qk[e + 3] * ev.w;
    }
    redq[seg * 64 + c] = s;
  }
  __syncthreads();
  if (t < 64) {
    float sv = redq[t] + redq[64 + t] + redq[128 + t] + redq[192 + t];
    float m = sv;
#pragma unroll
    for (int o = 32; o > 0; o >>= 1) m = fmaxf(m, __shfl_xor(m, o, 64));
    float e = __expf(sv - m);
    float sum = e;
#pragma unroll
    for (int o = 32; o > 0; o >>= 1) sum += __shfl_xor(sum, o, 64);
    pp[t] = e / sum;
  }
  __syncthreads();
  {
    float4 acc = {0.f, 0.f, 0.f, 0.f};
    const float* eb = p.enc + (i64)b * TENC * EE + 4 * t;
    for (int k = 0; k < 64; ++k) {
      float pk = pp[k];
      float4 ev = *(const float4*)(eb + (i64)k * EE);
      acc.x = fmaf(pk, ev.x, acc.x); acc.y = fmaf(pk, ev.y, acc.y);
      acc.z = fmaf(pk, ev.z, acc.z); acc.w = fmaf(pk, ev.w, acc.w);
    }
    *(float4*)&ctx[4 * t] = acc;
  }
  __syncthreads();
  {
    float4 a = {0, 0, 0, 0};
    const float* pv = wv + (i64)(es * 64) * EE + h * 64 + cg4;
#pragma unroll 4
    for (int e = 0; e < 64; ++e) {
      float xe = ctx[es * 64 + e];
      float4 w4 = *(const float4*)(pv + (i64)e * EE);
      a.x = fmaf(xe, w4.x, a.x); a.y = fmaf(xe, w4.y, a.y);
      a.z = fmaf(xe, w4.z, a.z); a.w = fmaf(xe, w4.w, a.w);
    }
    __syncthreads();
    *(float4*)&redq[es * 64 + cg4] = a;
  }
  __syncthreads();
  if (t < 64) {
    float o = 0.f;
#pragma unroll
    for (int s = 0; s < 16; ++s) o += redq[s * 64 + t];
    p.o2T[(i64)(h * 64 + t) * 16 + b] = o;
  }
  __syncthreads();
}

// ---------------- batched GEMV (8-deep pipeline) ----------------
__device__ __forceinline__ void dev_gemv(const float* __restrict__ xT, const float* __restrict__ W,
    float* __restrict__ part, int K, int N, int kchunk, int cb, int ns, int t, float* sm) {
  float* xs = sm;
  int e0 = ns * kchunk;
  int e1 = e0 + kchunk; if (e1 > K) e1 = K;
  int ne = e1 - e0;
  for (int idx = t; idx < ne * 16; idx += 256) xs[idx] = xT[(i64)e0 * 16 + idx];
  __syncthreads();
  int cc = cb * 256 + t;
  if (cc < N) {
    float acc[16];
#pragma unroll
    for (int b = 0; b < 16; ++b) acc[b] = 0.f;
    const float* Wp = W + (i64)e0 * N + cc;
    auto step = [&](int ei, float w) {
      const float4* xb4 = (const float4*)&xs[ei * 16];
      float4 x0 = xb4[0], x1 = xb4[1], x2 = xb4[2], x3 = xb4[3];
      acc[0] = fmaf(x0.x, w, acc[0]);  acc[1] = fmaf(x0.y, w, acc[1]);
      acc[2] = fmaf(x0.z, w, acc[2]);  acc[3] = fmaf(x0.w, w, acc[3]);
      acc[4] = fmaf(x1.x, w, acc[4]);  acc[5] = fmaf(x1.y, w, acc[5]);
      acc[6] = fmaf(x1.z, w, acc[6]);  acc[7] = fmaf(x1.w, w, acc[7]);
      acc[8] = fmaf(x2.x, w, acc[8]);  acc[9] = fmaf(x2.y, w, acc[9]);
      acc[10] = fmaf(x2.z, w, acc[10]); acc[11] = fmaf(x2.w, w, acc[11]);
      acc[12] = fmaf(x3.x, w, acc[12]); acc[13] = fmaf(x3.y, w, acc[13]);
      acc[14] = fmaf(x3.z, w, acc[14]); acc[15] = fmaf(x3.w, w, acc[15]);
    };
    int e = 0;
    for (; e + 8 <= ne; e += 8) {
      float w[8];
#pragma unroll
      for (int q = 0; q < 8; ++q) w[q] = Wp[(i64)(e + q) * N];
#pragma unroll
      for (int q = 0; q < 8; ++q) step(e + q, w[q]);
    }
    for (; e < ne; ++e) step(e, Wp[(i64)e * N]);
#pragma unroll
    for (int b = 0; b < 16; ++b) part[((i64)(ns * 16 + b)) * N + cc] = acc[b];
  }
  __syncthreads();
}

// ---------------- fused fc0+fc1 GEMV (8-deep) ----------------
__device__ __forceinline__ void dev_gemv2(const float* __restrict__ xT,
    const float* __restrict__ W0, const float* __restrict__ W1,
    float* __restrict__ p0, float* __restrict__ p1,
    int K, int N, int kchunk, int cb, int ns, int t, float* sm) {
  float* xs = sm;
  int e0 = ns * kchunk;
  int e1 = e0 + kchunk; if (e1 > K) e1 = K;
  int ne = e1 - e0;
  for (int idx = t; idx < ne * 16; idx += 256) xs[idx] = xT[(i64)e0 * 16 + idx];
  __syncthreads();
  int cc = cb * 256 + t;
  if (cc < N) {
    float a0[16], a1[16];
#pragma unroll
    for (int b = 0; b < 16; ++b) { a0[b] = 0.f; a1[b] = 0.f; }
    const float* W0p = W0 + (i64)e0 * N + cc;
    const float* W1p = W1 + (i64)e0 * N + cc;
    auto step = [&](int ei, float w0, float w1) {
      const float4* xb4 = (const float4*)&xs[ei * 16];
      float4 x0 = xb4[0], x1 = xb4[1], x2 = xb4[2], x3 = xb4[3];
      a0[0] = fmaf(x0.x, w0, a0[0]);  a1[0] = fmaf(x0.x, w1, a1[0]);
      a0[1] = fmaf(x0.y, w0, a0[1]);  a1[1] = fmaf(x0.y, w1, a1[1]);
      a0[2] = fmaf(x0.z, w0, a0[2]);  a1[2] = fmaf(x0.z, w1, a1[2]);
      a0[3] = fmaf(x0.w, w0, a0[3]);  a1[3] = fmaf(x0.w, w1, a1[3]);
      a0[4] = fmaf(x1.x, w0, a0[4]);  a1[4] = fmaf(x1.x, w1, a1[4]);
      a0[5] = fmaf(x1.y, w0, a0[5]);  a1[5] = fmaf(x1.y, w1, a1[5]);
      a0[6] = fmaf(x1.z, w0, a0[6]);  a1[6] = fmaf(x1.z, w1, a1[6]);
      a0[7] = fmaf(x1.w, w0, a0[7]);  a1[7] = fmaf(x1.w, w1, a1[7]);
      a0[8] = fmaf(x2.x, w0, a0[8]);  a1[8] = fmaf(x2.x, w1, a1[8]);
      a0[9] = fmaf(x2.y, w0, a0[9]);  a1[9] = fmaf(x2.y, w1, a1[9]);
      a0[10] = fmaf(x2.z, w0, a0[10]); a1[10] = fmaf(x2.z, w1, a1[10]);
      a0[11] = fmaf(x2.w, w0, a0[11]); a1[11] = fmaf(x2.w, w1, a1[11]);
      a0[12] = fmaf(x3.x, w0, a0[12]); a1[12] = fmaf(x3.x, w1, a1[12]);
      a0[13] = fmaf(x3.y, w0, a0[13]); a1[13] = fmaf(x3.y, w1, a1[13]);
      a0[14] = fmaf(x3.z, w0, a0[14]); a1[14] = fmaf(x3.z, w1, a1[14]);
      a0[15] = fmaf(x3.w, w0, a0[15]); a1[15] = fmaf(x3.w, w1, a1[15]);
    };
    int e = 0;
    for (; e + 8 <= ne; e += 8) {
      float u[8], v[8];
#pragma unroll
      for (int q = 0; q < 8; ++q) { u[q] = W0p[(i64)(e + q) * N]; v[q] = W1p[(i64)(e + q) * N]; }
#pragma unroll
      for (int q = 0; q < 8; ++q) step(e + q, u[q], v[q]);
    }
    for (; e < ne; ++e) step(e, W0p[(i64)e * N], W1p[(i64)e * N]);
#pragma unroll
    for (int b = 0; b < 16; ++b) {
      p0[((i64)(ns * 16 + b)) * N + cc] = a0[b];
      p1[((i64)(ns * 16 + b)) * N + cc] = a1[b];
    }
  }
  __syncthreads();
}

// ---------------- the persistent cooperative kernel ----------------
__global__ __launch_bounds__(256) void k_main(Params p) {
  cg::grid_group gridg = cg::this_grid();
  __shared__ float sm[SM_SZ];
  int bid = blockIdx.x, t = threadIdx.x;
  int ti = p.tok[0];
  if (bid < 16) dev_embed(p, bid, t, sm);
  else dev_copy(p, 0, bid, t, ti);
  gridg.sync();
  for (int l = 0; l < NL; ++l) {
    if (bid < 16) dev_ln1(p, l, bid, t, sm); else dev_copy(p, 1 + l * 4, bid, t, ti);
    gridg.sync();
    dev_sa(p, l, bid >> 4, bid & 15, t, ti, sm);
    gridg.sync();
    if (bid < 64) dev_gemv(p.oT, p.sao + (i64)l * EE * EE, p.h2p, EE, EE, 64, bid & 3, bid >> 2, t, sm);
    gridg.sync();
    if (bid < 16) dev_ln2(p, l, bid, t, sm); else dev_copy(p, 2 + l * 4, bid, t, ti);
    gridg.sync();
    dev_ca(p, l, bid >> 4, bid & 15, t, sm);
    gridg.sync();
    if (bid < 64) dev_gemv(p.o2T, p.cao + (i64)l * EE * EE, p.h4p, EE, EE, 64, bid & 3, bid >> 2, t, sm);
    gridg.sync();
    if (bid < 16) dev_ln3(p, l, bid, t, sm); else dev_copy(p, 3 + l * 4, bid, t, ti);
    gridg.sync();
    if (bid < 176) dev_gemv2(p.zT, p.fc0 + (i64)l * EE * GG, p.fc1 + (i64)l * EE * GG,
                             p.g0p, p.g1p, EE, GG, 64, bid / 16, bid % 16, t, sm);
    gridg.sync();
    if (bid < 16) dev_glu(p, l, bid, t, sm); else dev_copy(p, 4 + l * 4, bid, t, ti);
    gridg.sync();
    if (bid < 128) dev_gemv(p.w2T, p.fc2w + (i64)l * GG * EE, p.fc2p, GG, EE, 86, bid & 3, bid >> 2, t, sm);
    gridg.sync();
  }
  if (bid < 16) dev_finalln(p, bid, t, sm); else dev_copy(p, 49, bid, t, ti);
}

// ---------------- fallback wrappers (used only if coop launch fails) --------
__global__ __launch_bounds__(256) void k_copy(const float4* __restrict__ src,
                                              float4* __restrict__ dst, long n) {
  long i = (long)blockIdx.x * blockDim.x + threadIdx.x;
  long st = (long)gridDim.x * blockDim.x;
  for (; i < n; i += st) dst[i] = src[i];
}
__global__ __launch_bounds__(256) void kw_embed(Params p) {
  __shared__ float sm[SM_SZ];
  dev_embed(p, blockIdx.x, threadIdx.x, sm);
}
__global__ __launch_bounds__(256) void kw_ln1(Params p, int l) {
  __shared__ float sm[SM_SZ];
  dev_ln1(p, l, blockIdx.x, threadIdx.x, sm);
}
__global__ __launch_bounds__(256) void kw_sa(Params p, int l) {
  __shared__ float sm[SM_SZ];
  dev_sa(p, l, blockIdx.x >> 4, blockIdx.x & 15, threadIdx.x, p.tok[0], sm);
}
__global__ __launch_bounds__(256) void kw_ln2(Params p, int l) {
  __shared__ float sm[SM_SZ];
  dev_ln2(p, l, blockIdx.x, threadIdx.x, sm);
}
__global__ __launch_bounds__(256) void kw_ca(Params p, int l) {
  __shared__ float sm[SM_SZ];
  dev_ca(p, l, blockIdx.x >> 4, blockIdx.x & 15, threadIdx.x, sm);
}
__global__ __launch_bounds__(256) void kw_ln3(Params p, int l) {
  __shared__ float sm[SM_SZ];
  dev_ln3(p, l, blockIdx.x, threadIdx.x, sm);
}
__global__ __launch_bounds__(256) void kw_glu(Params p, int l) {
  __shared__ float sm[SM_SZ];
  dev_glu(p, l, blockIdx.x, threadIdx.x, sm);
}
__global__ __launch_bounds__(256) void kw_finalln(Params p) {
  __shared__ float sm[SM_SZ];
  dev_finalln(p, blockIdx.x, threadIdx.x, sm);
}
__global__ __launch_bounds__(256) void kw_gemv(const float* xT, const float* W, float* part,
                                              int K, int N, int kchunk) {
  __shared__ float sm[SM_SZ];
  dev_gemv(xT, W, part, K, N, kchunk, blockIdx.x, blockIdx.y, threadIdx.x, sm);
}
__global__ __launch_bounds__(256) void kw_gemv2(const float* xT, const float* W0, const float* W1,
                                                float* p0, float* p1, int K, int N, int kchunk) {
  __shared__ float sm[SM_SZ];
  dev_gemv2(xT, W0, W1, p0, p1, K, N, kchunk, blockIdx.x, blockIdx.y, threadIdx.x, sm);
}

// ---------------- CFG mix + exact top-50 threshold + probs ----------------
__device__ __forceinline__ unsigned fkey(float f) {
  unsigned u = __float_as_uint(f);
  return (u & 0x80000000u) ? ~u : (u | 0x80000000u);
}
#define TKJ 17
__global__ __launch_bounds__(1024) void k_cfg_topk(
    const float* __restrict__ part, float* __restrict__ probs) {
  __shared__ float sr[16];
  __shared__ int ir[16];
  int ic = blockIdx.x, t = threadIdx.x;
  float vals[TKJ];
  unsigned keys[TKJ];
  float mx = -3e38f;
#pragma unroll
  for (int j = 0; j < TKJ; ++j) {
    int v = j * 1024 + t;
    keys[j] = 0u; vals[j] = 0.f;
    if (v < VV) {
      float lo = 0.f, hi = 0.f;
#pragma unroll
      for (int n = 0; n < 8; ++n) {
        lo += part[((i64)(n * 16 + ic)) * VV + v];
        hi += part[((i64)(n * 16 + 8 + ic)) * VV + v];
      }
      float mval = -9.0f * lo + 10.0f * hi;
      vals[j] = mval; keys[j] = fkey(mval);
      mx = fmaxf(mx, mval);
    }
  }
  mx = bmax16(mx, sr);
  unsigned T = 0u;
  for (int bit = 31; bit >= 0; --bit) {
    unsigned cand = T | (1u << bit);
    int cnt = 0;
#pragma unroll
    for (int j = 0; j < TKJ; ++j) cnt += (keys[j] >= cand) ? 1 : 0;
    cnt = bsumI16(cnt, ir);
    if (cnt >= 50) T = cand;
  }
#pragma unroll
  for (int j = 0; j < TKJ; ++j) {
    int v = j * 1024 + t;
    if (v < VV) probs[(i64)ic * VV + v] = (keys[j] < T) ? 0.0f : expf(vals[j] - mx);
  }
}

// ---------------------------------------------------------------------------
extern "C" void kernel_launch(void* const* d_in, const int* in_sizes, int n_in,
                              void* d_out, int out_size, void* d_ws, size_t ws_size,
                              hipStream_t stream) {
  Params P;
  P.enc    = (const float*)d_in[1];
  P.ast_in = (const float*)d_in[2];
  P.prev   = (const int*)d_in[3];
  P.tok    = (const int*)d_in[4];
  P.embt   = (const float*)d_in[5];
  P.embp   = (const float*)d_in[6];
  P.lng    = (const float*)d_in[7];
  P.lnb    = (const float*)d_in[8];
  P.fing   = (const float*)d_in[9];
  P.finb   = (const float*)d_in[10];
  const float* lmw = (const float*)d_in[11];
  P.saq    = (const float*)d_in[12];
  P.sak    = (const float*)d_in[13];
  P.sav    = (const float*)d_in[14];
  P.sao    = (const float*)d_in[15];
  P.caq    = (const float*)d_in[16];
  P.cak    = (const float*)d_in[17];
  P.cav    = (const float*)d_in[18];
  P.cao    = (const float*)d_in[19];
  P.lnsg   = (const float*)d_in[20];
  P.lnsb   = (const float*)d_in[21];
  P.glug   = (const float*)d_in[22];
  P.glub   = (const float*)d_in[23];
  P.fc0    = (const float*)d_in[24];
  P.fc1    = (const float*)d_in[25];
  P.fc2w   = (const float*)d_in[26];

  float* probs = (float*)d_out;
  P.ast_out = probs + PROBS_N;

  char* wp = (char*)d_ws;
  auto alloc = [&](size_t nf) {
    float* p = (float*)wp;
    wp += ((nf * 4 + 255) / 256) * 256;
    return p;
  };
  P.x    = alloc(16 * EE);
  P.h1   = alloc(16 * EE);
  P.oT   = alloc((size_t)EE * 16);
  P.h2p  = alloc((size_t)16 * 16 * EE);
  P.h3   = alloc(16 * EE);
  P.o2T  = alloc((size_t)EE * 16);
  P.h4p  = alloc((size_t)16 * 16 * EE);
  P.zT   = alloc((size_t)EE * 16);
  P.g0p  = alloc((size_t)16 * 16 * GG);
  P.g1p  = alloc((size_t)16 * 16 * GG);
  P.w2T  = alloc((size_t)GG * 16);
  P.fc2p = alloc((size_t)32 * 16 * EE);
  P.xfT  = alloc((size_t)EE * 16);
  float* lmp = alloc((size_t)8 * 16 * VV);

  void* kargs[] = { (void*)&P };
  hipError_t err = hipLaunchCooperativeKernel((const void*)k_main, dim3(256), dim3(256),
                                              kargs, 0, stream);
  if (err != hipSuccess) {
    // fallback: equivalent multi-kernel sequence
    k_copy<<<2048, 256, 0, stream>>>((const float4*)P.ast_in, (float4*)P.ast_out,
                                     (long)NL * 32 * IMGT * EE / 4);
    kw_embed<<<16, 256, 0, stream>>>(P);
    for (int l = 0; l < NL; ++l) {
      i64 mo = (i64)l * EE * EE;
      kw_ln1<<<16, 256, 0, stream>>>(P, l);
      kw_sa<<<256, 256, 0, stream>>>(P, l);
      kw_gemv<<<dim3(4, 16), 256, 0, stream>>>(P.oT, P.sao + mo, P.h2p, EE, EE, 64);
      kw_ln2<<<16, 256, 0, stream>>>(P, l);
      kw_ca<<<256, 256, 0, stream>>>(P, l);
      kw_gemv<<<dim3(4, 16), 256, 0, stream>>>(P.o2T, P.cao + mo, P.h4p, EE, EE, 64);
      kw_ln3<<<16, 256, 0, stream>>>(P, l);
      kw_gemv2<<<dim3(11, 16), 256, 0, stream>>>(P.zT, P.fc0 + (i64)l * EE * GG,
                                                 P.fc1 + (i64)l * EE * GG, P.g0p, P.g1p,
                                                 EE, GG, 64);
      kw_glu<<<16, 256, 0, stream>>>(P, l);
      kw_gemv<<<dim3(4, 32), 256, 0, stream>>>(P.w2T, P.fc2w + (i64)l * GG * EE, P.fc2p,
                                               GG, EE, 86);
    }
    kw_finalln<<<16, 256, 0, stream>>>(P);
  }
  kw_gemv<<<dim3(65, 8), 256, 0, stream>>>(P.xfT, lmw, lmp, EE, VV, 128);
  k_cfg_topk<<<8, 1024, 0, stream>>>(lmp, probs);
}